// Round 1
// baseline (1594.878 us; speedup 1.0000x reference)
//
#include <hip/hip_runtime.h>

#define NEG_SLOPE 0.2f

__device__ __forceinline__ float leakyf(float x) {
    return x >= 0.f ? x : NEG_SLOPE * x;
}

// ---------------- face normals: atomic scatter ----------------
__global__ __launch_bounds__(256)
void normals_kernel(const float* __restrict__ v, const int* __restrict__ f,
                    float* __restrict__ vn, int nf) {
    int i = blockIdx.x * 256 + threadIdx.x;
    if (i >= nf) return;
    int i0 = f[3 * i], i1 = f[3 * i + 1], i2 = f[3 * i + 2];
    float p0x = v[3 * i0], p0y = v[3 * i0 + 1], p0z = v[3 * i0 + 2];
    float ux = v[3 * i1] - p0x, uy = v[3 * i1 + 1] - p0y, uz = v[3 * i1 + 2] - p0z;
    float wx = v[3 * i2] - p0x, wy = v[3 * i2 + 1] - p0y, wz = v[3 * i2 + 2] - p0z;
    float fx = uy * wz - uz * wy;
    float fy = uz * wx - ux * wz;
    float fz = ux * wy - uy * wx;
    atomicAdd(&vn[3 * i0 + 0], fx); atomicAdd(&vn[3 * i0 + 1], fy); atomicAdd(&vn[3 * i0 + 2], fz);
    atomicAdd(&vn[3 * i1 + 0], fx); atomicAdd(&vn[3 * i1 + 1], fy); atomicAdd(&vn[3 * i1 + 2], fz);
    atomicAdd(&vn[3 * i2 + 0], fx); atomicAdd(&vn[3 * i2 + 1], fy); atomicAdd(&vn[3 * i2 + 2], fz);
}

// ---------------- trilinear sampling of 5x5x5 cube per vertex ----------------
// cubes row = 128 floats (125 samples + 3 zero pad).  Thread q maps to
// (a=q%5, b=(q/5)%5, c=q/25) so consecutive lanes walk the x (innermost) axis
// of the volume; writes to r = 25a+5b+c (reference ordering).
__global__ __launch_bounds__(256)
void sample_kernel(const float* __restrict__ v, const float* __restrict__ vol,
                   float* __restrict__ cubes, int m_start, int cnt) {
    int tid = blockIdx.x * 256 + threadIdx.x;
    int ml = tid >> 7, q = tid & 127;
    if (ml >= cnt) return;
    float* dst = cubes + (size_t)ml * 128;
    if (q >= 125) { dst[q] = 0.f; return; }
    int a = q % 5, b = (q / 5) % 5, c = q / 25;
    int m = m_start + ml;
    // grid = linspace(-3, 2, 5); shift = (g/192)*2   (matches reference rounding)
    float ga = -3.f + 1.25f * (float)a;
    float gb = -3.f + 1.25f * (float)b;
    float gc = -3.f + 1.25f * (float)c;
    float px = v[3 * m + 0] + ga / 192.f * 2.f;
    float py = v[3 * m + 1] + gb / 192.f * 2.f;
    float pz = v[3 * m + 2] + gc / 192.f * 2.f;
    float ix = fminf(fmaxf((px + 1.f) * 0.5f * 191.f, 0.f), 191.f);
    float iy = fminf(fmaxf((py + 1.f) * 0.5f * 191.f, 0.f), 191.f);
    float iz = fminf(fmaxf((pz + 1.f) * 0.5f * 191.f, 0.f), 191.f);
    float xf = floorf(ix), yf = floorf(iy), zf = floorf(iz);
    float wxv = ix - xf, wyv = iy - yf, wzv = iz - zf;
    int x0 = (int)xf, y0 = (int)yf, z0 = (int)zf;
    int x1 = min(x0 + 1, 191), y1 = min(y0 + 1, 191), z1 = min(z0 + 1, 191);
    const float* pz0y0 = vol + z0 * 36864 + y0 * 192;
    const float* pz0y1 = vol + z0 * 36864 + y1 * 192;
    const float* pz1y0 = vol + z1 * 36864 + y0 * 192;
    const float* pz1y1 = vol + z1 * 36864 + y1 * 192;
    float c000 = pz0y0[x0], c001 = pz0y0[x1];
    float c010 = pz0y1[x0], c011 = pz0y1[x1];
    float c100 = pz1y0[x0], c101 = pz1y0[x1];
    float c110 = pz1y1[x0], c111 = pz1y1[x1];
    float omx = 1.f - wxv, omy = 1.f - wyv, omz = 1.f - wzv;
    float c00 = c000 * omx + c001 * wxv;
    float c01 = c010 * omx + c011 * wxv;
    float c10 = c100 * omx + c101 * wxv;
    float c11 = c110 * omx + c111 * wxv;
    float c0 = c00 * omy + c01 * wyv;
    float c1 = c10 * omy + c11 * wyv;
    dst[25 * a + 5 * b + c] = c0 * omz + c1 * wzv;
}

// ---------------- pad Wconv (128x125) -> (128x128) with zeros ----------------
__global__ __launch_bounds__(256)
void wpad_kernel(const float* __restrict__ Wconv, float* __restrict__ wpad) {
    int i = blockIdx.x * 256 + threadIdx.x;  // 16384 total
    int ch = i >> 7, k = i & 127;
    wpad[i] = (k < 125) ? Wconv[ch * 125 + k] : 0.f;
}

// ---------------- z_point = leaky([v, vn_normalized] @ W1^T + b1) ----------------
__global__ __launch_bounds__(128)
void point_kernel(const float* __restrict__ v, const float* __restrict__ vn,
                  const float* __restrict__ W1, const float* __restrict__ b1,
                  float* __restrict__ out, int m_start, int cnt) {
    int ml = blockIdx.x;
    if (ml >= cnt) return;
    int n = threadIdx.x;  // 0..127
    int m = m_start + ml;
    float x0 = v[3 * m], x1 = v[3 * m + 1], x2 = v[3 * m + 2];
    float nx = vn[3 * m], ny = vn[3 * m + 1], nz = vn[3 * m + 2];
    float nrm = fmaxf(sqrtf(nx * nx + ny * ny + nz * nz), 1e-6f);
    nx /= nrm; ny /= nrm; nz /= nrm;
    const float* w = W1 + n * 6;
    float z = b1[n] + x0 * w[0] + x1 * w[1] + x2 * w[2] + nx * w[3] + ny * w[4] + nz * w[5];
    out[(size_t)m * 256 + n] = leakyf(z);
}

// ---------------- generic tiled fp32 GEMM: out = leaky(A @ W^T + bias) ----------------
// A: Meff x K row-major (stride K), K % 64 == 0.  W: N x K row-major, N = gridDim.y*128.
// out[m*OS + OC + n].  Block tile 64m x 128n, KC=64, 256 threads, 4m x 8n per thread.
// LDS stores A/W transposed ([k][m] / [k][n]) with XOR swizzle col^(((k>>2)&7)<<2)
// so staging writes and b128 compute reads are bank-friendly.
__global__ __launch_bounds__(256)
void gemm_leaky(const float* __restrict__ A, const float* __restrict__ W,
                const float* __restrict__ bias, float* __restrict__ out,
                int K, int Meff, int OS, int OC) {
    __shared__ float As[64 * 64];
    __shared__ float Ws[64 * 128];
    const int t = threadIdx.x;
    const int m0 = blockIdx.x * 64;
    const int n0 = blockIdx.y * 128;
    const int tn = t & 15, tm = t >> 4;

    float acc[4][8];
#pragma unroll
    for (int i = 0; i < 4; ++i)
#pragma unroll
        for (int j = 0; j < 8; ++j) acc[i][j] = 0.f;

    const int nk = K >> 6;
    for (int ck = 0; ck < nk; ++ck) {
        const int kc = ck << 6;
        // stage A tile 64 rows x 64 k (transposed into LDS)
#pragma unroll
        for (int i = 0; i < 4; ++i) {
            int idx = t + i * 256;
            int row = idx >> 4, k4 = idx & 15;
            float4 val = make_float4(0.f, 0.f, 0.f, 0.f);
            int m = m0 + row;
            if (m < Meff) val = *(const float4*)(A + (size_t)m * K + kc + 4 * k4);
            int s = (k4 & 7) << 2;
            int pc = row ^ s;
            As[(4 * k4 + 0) * 64 + pc] = val.x;
            As[(4 * k4 + 1) * 64 + pc] = val.y;
            As[(4 * k4 + 2) * 64 + pc] = val.z;
            As[(4 * k4 + 3) * 64 + pc] = val.w;
        }
        // stage W tile 128 rows x 64 k (transposed into LDS)
#pragma unroll
        for (int i = 0; i < 8; ++i) {
            int idx = t + i * 256;
            int n = idx >> 4, k4 = idx & 15;
            float4 val = *(const float4*)(W + (size_t)(n0 + n) * K + kc + 4 * k4);
            int s = (k4 & 7) << 2;
            int pc = n ^ s;
            Ws[(4 * k4 + 0) * 128 + pc] = val.x;
            Ws[(4 * k4 + 1) * 128 + pc] = val.y;
            Ws[(4 * k4 + 2) * 128 + pc] = val.z;
            Ws[(4 * k4 + 3) * 128 + pc] = val.w;
        }
        __syncthreads();
#pragma unroll 8
        for (int k = 0; k < 64; ++k) {
            int s = ((k >> 2) & 7) << 2;
            float4 av = *(const float4*)&As[k * 64 + ((4 * tm) ^ s)];
            int o = (8 * tn) ^ s;
            float4 b0 = *(const float4*)&Ws[k * 128 + o];        // logical n = 8tn..+3
            float4 b1v = *(const float4*)&Ws[k * 128 + (o ^ 4)]; // logical n = 8tn+4..+7
            float a_[4] = {av.x, av.y, av.z, av.w};
            float b_[8] = {b0.x, b0.y, b0.z, b0.w, b1v.x, b1v.y, b1v.z, b1v.w};
#pragma unroll
            for (int i = 0; i < 4; ++i)
#pragma unroll
                for (int j = 0; j < 8; ++j)
                    acc[i][j] = fmaf(a_[i], b_[j], acc[i][j]);
        }
        __syncthreads();
    }

    float bv[8];
#pragma unroll
    for (int j = 0; j < 8; ++j) bv[j] = bias[n0 + 8 * tn + j];
#pragma unroll
    for (int i = 0; i < 4; ++i) {
        int m = m0 + 4 * tm + i;
        if (m < Meff) {
            float4 o0, o1;
            o0.x = leakyf(acc[i][0] + bv[0]);
            o0.y = leakyf(acc[i][1] + bv[1]);
            o0.z = leakyf(acc[i][2] + bv[2]);
            o0.w = leakyf(acc[i][3] + bv[3]);
            o1.x = leakyf(acc[i][4] + bv[4]);
            o1.y = leakyf(acc[i][5] + bv[5]);
            o1.z = leakyf(acc[i][6] + bv[6]);
            o1.w = leakyf(acc[i][7] + bv[7]);
            float* p = out + (size_t)m * OS + OC + n0 + 8 * tn;
            *(float4*)(p) = o0;
            *(float4*)(p + 4) = o1;
        }
    }
}

extern "C" void kernel_launch(void* const* d_in, const int* in_sizes, int n_in,
                              void* d_out, int out_size, void* d_ws, size_t ws_size,
                              hipStream_t stream) {
    const float* v = (const float*)d_in[0];
    const int* f = (const int*)d_in[1];
    const float* vol = (const float*)d_in[2];
    const float* Wconv = (const float*)d_in[3];
    const float* bconv = (const float*)d_in[4];
    const float* Wlfc = (const float*)d_in[5];
    const float* blfc = (const float*)d_in[6];
    const float* W1 = (const float*)d_in[7];
    const float* b1 = (const float*)d_in[8];
    const float* W2 = (const float*)d_in[9];
    const float* b2 = (const float*)d_in[10];
    const float* W3 = (const float*)d_in[11];
    const float* b3 = (const float*)d_in[12];
    float* out = (float*)d_out;
    const int M = in_sizes[0] / 3;
    const int NF = in_sizes[1] / 3;

    // workspace layout: vn (M*3) | wpad (128*128) | chunked {cubes,z0,h}
    char* base = (char*)d_ws;
    float* vn = (float*)base;
    size_t off = ((size_t)M * 3 * 4 + 255) & ~(size_t)255;
    float* wpad = (float*)(base + off);
    off += (size_t)128 * 128 * 4;
    size_t avail = ws_size > off ? ws_size - off : 0;
    size_t Mpad = ((size_t)M + 63) & ~(size_t)63;
    size_t chm = avail / 3072;  // (128 + 128 + 512) floats per row
    chm &= ~(size_t)63;
    if (chm > Mpad) chm = Mpad;
    if (chm < 64) chm = 64;  // minimal fallback
    float* cubes = (float*)(base + off);
    float* z0 = cubes + chm * 128;
    float* h = z0 + chm * 128;

    hipMemsetAsync(vn, 0, (size_t)M * 3 * 4, stream);
    normals_kernel<<<(NF + 255) / 256, 256, 0, stream>>>(v, f, vn, NF);
    wpad_kernel<<<64, 256, 0, stream>>>(Wconv, wpad);

    for (size_t ms = 0; ms < (size_t)M; ms += chm) {
        int cnt = (int)(((size_t)M - ms) < chm ? ((size_t)M - ms) : chm);
        int mb = (cnt + 63) / 64;
        sample_kernel<<<((size_t)cnt * 128 + 255) / 256, 256, 0, stream>>>(v, vol, cubes, (int)ms, cnt);
        // z0 = leaky(cubes @ Wconv^T + bconv)          (K=128 padded, N=128)
        gemm_leaky<<<dim3(mb, 1), 256, 0, stream>>>(cubes, wpad, bconv, z0, 128, cnt, 128, 0);
        // z_local -> d_out cols [128:256)              (K=128, N=128)
        gemm_leaky<<<dim3(mb, 1), 256, 0, stream>>>(z0, Wlfc, blfc, out + ms * 256, 128, cnt, 256, 128);
        // z_point -> d_out cols [0:128)
        point_kernel<<<cnt, 128, 0, stream>>>(v, vn, W1, b1, out, (int)ms, cnt);
        // h = leaky(z_cat @ W2^T + b2)                 (K=256, N=512)
        gemm_leaky<<<dim3(mb, 4), 256, 0, stream>>>(out + ms * 256, W2, b2, h, 256, cnt, 512, 0);
        // out = leaky(h @ W3^T + b3)                   (K=512, N=256)
        gemm_leaky<<<dim3(mb, 2), 256, 0, stream>>>(h, W3, b3, out + ms * 256, 512, cnt, 256, 0);
    }
}

// Round 2
// 558.274 us; speedup vs baseline: 2.8568x; 2.8568x over previous
//
#include <hip/hip_runtime.h>
#include <hip/hip_fp16.h>

#define NEG_SLOPE 0.2f

using f16x8 = __attribute__((ext_vector_type(8))) _Float16;
using f32x4 = __attribute__((ext_vector_type(4))) float;

__device__ __forceinline__ float leakyf(float x) { return x >= 0.f ? x : NEG_SLOPE * x; }

__device__ __forceinline__ void gload_lds16(const void* g, void* l) {
    __builtin_amdgcn_global_load_lds(
        (const __attribute__((address_space(1))) unsigned int*)g,
        (__attribute__((address_space(3))) unsigned int*)l, 16, 0, 0);
}

// ---------------- face normals: atomic scatter ----------------
__global__ __launch_bounds__(256)
void normals_kernel(const float* __restrict__ v, const int* __restrict__ f,
                    float* __restrict__ vn, int nf) {
    int i = blockIdx.x * 256 + threadIdx.x;
    if (i >= nf) return;
    int i0 = f[3 * i], i1 = f[3 * i + 1], i2 = f[3 * i + 2];
    float p0x = v[3 * i0], p0y = v[3 * i0 + 1], p0z = v[3 * i0 + 2];
    float ux = v[3 * i1] - p0x, uy = v[3 * i1 + 1] - p0y, uz = v[3 * i1 + 2] - p0z;
    float wx = v[3 * i2] - p0x, wy = v[3 * i2 + 1] - p0y, wz = v[3 * i2 + 2] - p0z;
    float fx = uy * wz - uz * wy;
    float fy = uz * wx - ux * wz;
    float fz = ux * wy - uy * wx;
    atomicAdd(&vn[3 * i0 + 0], fx); atomicAdd(&vn[3 * i0 + 1], fy); atomicAdd(&vn[3 * i0 + 2], fz);
    atomicAdd(&vn[3 * i1 + 0], fx); atomicAdd(&vn[3 * i1 + 1], fy); atomicAdd(&vn[3 * i1 + 2], fz);
    atomicAdd(&vn[3 * i2 + 0], fx); atomicAdd(&vn[3 * i2 + 1], fy); atomicAdd(&vn[3 * i2 + 2], fz);
}

// ---------------- trilinear sampling of 5x5x5 cube per vertex (fp16 out) -------
__global__ __launch_bounds__(256)
void sample_kernel(const float* __restrict__ v, const float* __restrict__ vol,
                   __half* __restrict__ cubes, int m_start, int cnt) {
    int tid = blockIdx.x * 256 + threadIdx.x;
    int ml = tid >> 7, q = tid & 127;
    if (ml >= cnt) return;
    __half* dst = cubes + (size_t)ml * 128;
    if (q >= 125) { dst[q] = __float2half(0.f); return; }
    int a = q % 5, b = (q / 5) % 5, c = q / 25;
    int m = m_start + ml;
    // grid = linspace(-3, 2, 5) (python -K//2 = -3); shift = g/192*2
    float ga = -3.f + 1.25f * (float)a;
    float gb = -3.f + 1.25f * (float)b;
    float gc = -3.f + 1.25f * (float)c;
    float px = v[3 * m + 0] + ga / 192.f * 2.f;
    float py = v[3 * m + 1] + gb / 192.f * 2.f;
    float pz = v[3 * m + 2] + gc / 192.f * 2.f;
    float ix = fminf(fmaxf((px + 1.f) * 0.5f * 191.f, 0.f), 191.f);
    float iy = fminf(fmaxf((py + 1.f) * 0.5f * 191.f, 0.f), 191.f);
    float iz = fminf(fmaxf((pz + 1.f) * 0.5f * 191.f, 0.f), 191.f);
    float xf = floorf(ix), yf = floorf(iy), zf = floorf(iz);
    float wxv = ix - xf, wyv = iy - yf, wzv = iz - zf;
    int x0 = (int)xf, y0 = (int)yf, z0 = (int)zf;
    int x1 = min(x0 + 1, 191), y1 = min(y0 + 1, 191), z1 = min(z0 + 1, 191);
    const float* pz0y0 = vol + z0 * 36864 + y0 * 192;
    const float* pz0y1 = vol + z0 * 36864 + y1 * 192;
    const float* pz1y0 = vol + z1 * 36864 + y0 * 192;
    const float* pz1y1 = vol + z1 * 36864 + y1 * 192;
    float c000 = pz0y0[x0], c001 = pz0y0[x1];
    float c010 = pz0y1[x0], c011 = pz0y1[x1];
    float c100 = pz1y0[x0], c101 = pz1y0[x1];
    float c110 = pz1y1[x0], c111 = pz1y1[x1];
    float omx = 1.f - wxv, omy = 1.f - wyv, omz = 1.f - wzv;
    float c00 = c000 * omx + c001 * wxv;
    float c01 = c010 * omx + c011 * wxv;
    float c10 = c100 * omx + c101 * wxv;
    float c11 = c110 * omx + c111 * wxv;
    float c0 = c00 * omy + c01 * wyv;
    float c1 = c10 * omy + c11 * wyv;
    dst[25 * a + 5 * b + c] = __float2half(c0 * omz + c1 * wzv);
}

// ------------- convert all weights to fp16 (pad Wconv 125->128) -------------
__global__ __launch_bounds__(256)
void prep_weights(const float* __restrict__ Wconv, const float* __restrict__ Wlfc,
                  const float* __restrict__ W2, const float* __restrict__ W3,
                  __half* __restrict__ wpadh, __half* __restrict__ wlfch,
                  __half* __restrict__ w2h, __half* __restrict__ w3h) {
    int b = blockIdx.x, t = threadIdx.x;
    if (b < 64) {
        int i = b * 256 + t; int ch = i >> 7, k = i & 127;
        wpadh[i] = __float2half(k < 125 ? Wconv[ch * 125 + k] : 0.f);
    } else if (b < 128) {
        int i = (b - 64) * 256 + t; wlfch[i] = __float2half(Wlfc[i]);
    } else if (b < 640) {
        int i = (b - 128) * 256 + t; w2h[i] = __float2half(W2[i]);
    } else {
        int i = (b - 640) * 256 + t; w3h[i] = __float2half(W3[i]);
    }
}

// ---- z_point = leaky([v, vn_norm] @ W1^T + b1) -> zcat cols [0:128) fp16 ----
__global__ __launch_bounds__(256)
void point_kernel(const float* __restrict__ v, const float* __restrict__ vn,
                  const float* __restrict__ W1, const float* __restrict__ b1,
                  __half* __restrict__ zcat, int m_start, int cnt) {
    int ml = blockIdx.x * 2 + (threadIdx.x >> 7);
    if (ml >= cnt) return;
    int n = threadIdx.x & 127;
    int m = m_start + ml;
    float x0 = v[3 * m], x1 = v[3 * m + 1], x2 = v[3 * m + 2];
    float nx = vn[3 * m], ny = vn[3 * m + 1], nz = vn[3 * m + 2];
    float nrm = fmaxf(sqrtf(nx * nx + ny * ny + nz * nz), 1e-6f);
    nx /= nrm; ny /= nrm; nz /= nrm;
    const float* w = W1 + n * 6;
    float z = b1[n] + x0 * w[0] + x1 * w[1] + x2 * w[2] + nx * w[3] + ny * w[4] + nz * w[5];
    zcat[(size_t)ml * 256 + n] = __float2half(leakyf(z));
}

// ---------------- MFMA fp16 GEMM: out = leaky(A @ W^T + bias) ----------------
// A: [rows][K] fp16, W: [N][K] fp16, K%64==0, N = gridDim.y*128.
// Tile 128x128, BK=64, 256 thr = 4 waves (2x2), wave = 64x64 = 4x4 frags of
// v_mfma_f32_16x16x32_f16.  LDS tiles [128][64] fp16 with XOR swizzle
// byte ^= ((row&7)<<4); staged via global_load_lds w=16 with pre-swizzled
// global source (linear LDS dest).  Epilogue: fp16 plane or fp32 final.
template<bool F32OUT>
__global__ __launch_bounds__(256)
void gemm_mfma(const __half* __restrict__ A, const __half* __restrict__ W,
               const float* __restrict__ bias, void* __restrict__ outp,
               int K, int Meff, int OS, int OC) {
    __shared__ __half As[8192];
    __shared__ __half Bs[8192];
    const int t = threadIdx.x;
    const int lane = t & 63, wave = t >> 6;
    const int lr = lane & 15, lg = lane >> 4;
    const int wm = wave >> 1, wn = wave & 1;
    const int m0 = blockIdx.x * 128, n0 = blockIdx.y * 128;

    // staging: thread t stages 16B; linear LDS byte = i*4096 + t*16.
    // row = i*32 + (t>>3); swizzled source byte-col = ((t&7)<<4) ^ (((t>>3)&7)<<4)
    const int srow = t >> 3;
    const int scb = ((t & 7) << 4) ^ (((t >> 3) & 7) << 4);
    const __half* Ag = A + (size_t)(m0 + srow) * K + (scb >> 1);
    const __half* Wg = W + (size_t)(n0 + srow) * K + (scb >> 1);
    __half* Al = As + wave * 512;   // wave-uniform dest (HW adds lane*16B)
    __half* Bl = Bs + wave * 512;

    // fragment read offsets: row = w*64 + fm*16 + lr  (row&7 == lr&7)
    const int swz = (lr & 7) << 4;
    const char* aB = (const char*)As + (wm * 64 + lr) * 128;
    const char* bB = (const char*)Bs + (wn * 64 + lr) * 128;
    const int k0 = (lg * 16) ^ swz;
    const int k1 = (64 + lg * 16) ^ swz;

    f32x4 acc[4][4] = {};

    for (int kc = 0; kc < K; kc += 64) {
#pragma unroll
        for (int i = 0; i < 4; ++i) {
            gload_lds16(Ag + (size_t)i * 32 * K + kc, Al + i * 2048);
            gload_lds16(Wg + (size_t)i * 32 * K + kc, Bl + i * 2048);
        }
        __syncthreads();  // drains vmcnt(0) before barrier
        f16x8 af[4], bf[4];
#pragma unroll
        for (int fx = 0; fx < 4; ++fx) {
            af[fx] = *(const f16x8*)(aB + fx * 2048 + k0);
            bf[fx] = *(const f16x8*)(bB + fx * 2048 + k0);
        }
#pragma unroll
        for (int fm = 0; fm < 4; ++fm)
#pragma unroll
            for (int fn = 0; fn < 4; ++fn)
                acc[fm][fn] = __builtin_amdgcn_mfma_f32_16x16x32_f16(af[fm], bf[fn], acc[fm][fn], 0, 0, 0);
#pragma unroll
        for (int fx = 0; fx < 4; ++fx) {
            af[fx] = *(const f16x8*)(aB + fx * 2048 + k1);
            bf[fx] = *(const f16x8*)(bB + fx * 2048 + k1);
        }
#pragma unroll
        for (int fm = 0; fm < 4; ++fm)
#pragma unroll
            for (int fn = 0; fn < 4; ++fn)
                acc[fm][fn] = __builtin_amdgcn_mfma_f32_16x16x32_f16(af[fm], bf[fn], acc[fm][fn], 0, 0, 0);
        __syncthreads();
    }

    // C/D layout: col = lane&15, row = (lane>>4)*4 + reg   [m89-verified]
    float bv[4];
#pragma unroll
    for (int fn = 0; fn < 4; ++fn) bv[fn] = bias[n0 + wn * 64 + fn * 16 + lr];
    const int rbase = m0 + wm * 64 + lg * 4;
    const int cbase = OC + n0 + wn * 64 + lr;
#pragma unroll
    for (int fm = 0; fm < 4; ++fm) {
#pragma unroll
        for (int r = 0; r < 4; ++r) {
            int row = rbase + fm * 16 + r;
            if (row < Meff) {
#pragma unroll
                for (int fn = 0; fn < 4; ++fn) {
                    float val = leakyf(acc[fm][fn][r] + bv[fn]);
                    if (F32OUT)
                        ((float*)outp)[(size_t)row * OS + cbase + fn * 16] = val;
                    else
                        ((__half*)outp)[(size_t)row * OS + cbase + fn * 16] = __float2half(val);
                }
            }
        }
    }
}

extern "C" void kernel_launch(void* const* d_in, const int* in_sizes, int n_in,
                              void* d_out, int out_size, void* d_ws, size_t ws_size,
                              hipStream_t stream) {
    const float* v = (const float*)d_in[0];
    const int* f = (const int*)d_in[1];
    const float* vol = (const float*)d_in[2];
    const float* Wconv = (const float*)d_in[3];
    const float* bconv = (const float*)d_in[4];
    const float* Wlfc = (const float*)d_in[5];
    const float* blfc = (const float*)d_in[6];
    const float* W1 = (const float*)d_in[7];
    const float* b1 = (const float*)d_in[8];
    const float* W2 = (const float*)d_in[9];
    const float* b2 = (const float*)d_in[10];
    const float* W3 = (const float*)d_in[11];
    const float* b3 = (const float*)d_in[12];
    float* out = (float*)d_out;
    const int M = in_sizes[0] / 3;
    const int NF = in_sizes[1] / 3;

    // ws layout: vn fp32 | wpadh | wlfch | w2h | w3h | chunk{cubes,z0,zcat,h} fp16
    char* base = (char*)d_ws;
    float* vn = (float*)base;
    size_t off = ((size_t)M * 12 + 255) & ~(size_t)255;
    __half* wpadh = (__half*)(base + off); off += 32768;
    __half* wlfch = (__half*)(base + off); off += 32768;
    __half* w2h = (__half*)(base + off); off += 262144;
    __half* w3h = (__half*)(base + off); off += 262144;
    size_t avail = ws_size > off ? ws_size - off : 0;
    size_t Mpad = ((size_t)M + 127) & ~(size_t)127;
    size_t chm = (avail / 2048) & ~(size_t)127;  // 2048 B per row of fp16 scratch
    if (chm > Mpad) chm = Mpad;
    if (chm < 128) chm = 128;
    __half* cubes = (__half*)(base + off);
    __half* z0 = cubes + chm * 128;
    __half* zcat = z0 + chm * 128;
    __half* h = zcat + chm * 256;

    hipMemsetAsync(vn, 0, (size_t)M * 12, stream);
    normals_kernel<<<(NF + 255) / 256, 256, 0, stream>>>(v, f, vn, NF);
    prep_weights<<<1152, 256, 0, stream>>>(Wconv, Wlfc, W2, W3, wpadh, wlfch, w2h, w3h);

    for (size_t ms = 0; ms < (size_t)M; ms += chm) {
        size_t rem = (size_t)M - ms;
        int cnt = (int)(rem < chm ? rem : chm);
        int mb = (cnt + 127) / 128;
        sample_kernel<<<(cnt * 128 + 255) / 256, 256, 0, stream>>>(v, vol, cubes, (int)ms, cnt);
        // z0 = leaky(cubes @ Wconv^T + bconv)      K=128, N=128
        gemm_mfma<false><<<dim3(mb, 1), 256, 0, stream>>>(cubes, wpadh, bconv, z0, 128, mb * 128, 128, 0);
        // zcat[:,128:256) = leaky(z0 @ Wlfc^T)     K=128, N=128
        gemm_mfma<false><<<dim3(mb, 1), 256, 0, stream>>>(z0, wlfch, blfc, zcat, 128, mb * 128, 256, 128);
        // zcat[:,0:128) = z_point
        point_kernel<<<(cnt + 1) / 2, 256, 0, stream>>>(v, vn, W1, b1, zcat, (int)ms, cnt);
        // h = leaky(zcat @ W2^T + b2)              K=256, N=512
        gemm_mfma<false><<<dim3(mb, 4), 256, 0, stream>>>(zcat, w2h, b2, h, 256, mb * 128, 512, 0);
        // out = leaky(h @ W3^T + b3)               K=512, N=256  (fp32 final)
        gemm_mfma<true><<<dim3(mb, 2), 256, 0, stream>>>(h, w3h, b3, out + ms * 256, 512, cnt, 256, 0);
    }
}